// Round 1
// baseline (4127.180 us; speedup 1.0000x reference)
//
#include <hip/hip_runtime.h>

#define HID 128
#define CELLS 98304
#define NE 250000
#define NSTEPS 2

typedef __attribute__((ext_vector_type(8))) short short8;
typedef __attribute__((ext_vector_type(4))) float f32x4;
typedef unsigned short u16;

// pi permutation: stored slot s holds natural feature perm(s)
__device__ __forceinline__ int permf(int s) { return ((s & 7) << 4) | (s >> 3); }

__device__ __forceinline__ u16 f2bf(float f) {
  unsigned int u = __builtin_bit_cast(unsigned int, f);
  u += 0x7fffu + ((u >> 16) & 1u);
  return (u16)(u >> 16);
}
__device__ __forceinline__ float bf2f(u16 s) {
  unsigned int u = ((unsigned int)s) << 16;
  return __builtin_bit_cast(float, u);
}
__device__ __forceinline__ float sigm(float x) { return 1.f / (1.f + __expf(-x)); }
__device__ __forceinline__ float tanha(float x) { return 1.f - 2.f / (__expf(2.f * x) + 1.f); }

// ---------------- prep: bf16-convert + pi-permute all weights ----------------
__global__ void prep_kernel(
    const float* __restrict__ W0, const float* __restrict__ W1,
    const float* __restrict__ W2, const float* __restrict__ W3,
    const float* __restrict__ b0, const float* __restrict__ b1,
    const float* __restrict__ b2, const float* __restrict__ b3,
    const float* __restrict__ Wih, const float* __restrict__ Whh,
    const float* __restrict__ embed, const float* __restrict__ sw,
    u16* __restrict__ W0b, u16* __restrict__ W1b,
    u16* __restrict__ W2b, u16* __restrict__ W3b,
    u16* __restrict__ Wcb, float* __restrict__ bp,
    u16* __restrict__ embp, float* __restrict__ swp)
{
  int idx = blockIdx.x * 256 + threadIdx.x;
  if (idx < 65536) {  // W0b [et][n][s], s in [0,256): k_nat = perm on each 128-half
    int s = idx & 255, n = (idx >> 8) & 127, et = idx >> 15;
    int k = (s < 128) ? permf(s) : (128 + permf(s & 127));
    W0b[idx] = f2bf(W0[(et * 128 + n) * 256 + k]);
    return;
  }
  idx -= 65536;
  if (idx < 98304) {  // W1b/W2b/W3b [et][n][s]
    int which = idx >> 15, r = idx & 32767;
    int s = r & 127, n = (r >> 7) & 127, et = r >> 14;
    const float* W = which == 0 ? W1 : (which == 1 ? W2 : W3);
    u16* Wb = which == 0 ? W1b : (which == 1 ? W2b : W3b);
    Wb[r] = f2bf(W[(et * 128 + n) * 128 + permf(s)]);
    return;
  }
  idx -= 98304;
  if (idx < 262144) {  // Wcat [n=512][s=512] = [Wih(x|m0|m1) | Whh], per-128-block perm
    int s = idx & 511, n = idx >> 9;
    int blk = s >> 7, s7 = s & 127;
    float v = (blk < 3) ? Wih[n * 384 + blk * 128 + permf(s7)] : Whh[n * 128 + permf(s7)];
    Wcb[idx] = f2bf(v);
    return;
  }
  idx -= 262144;
  if (idx < 1024) {  // biases [layer 0..3][et][s] pi-order
    int l = idx >> 8, r = idx & 255;
    int et = r >> 7, s = r & 127;
    const float* b = l == 0 ? b0 : (l == 1 ? b1 : (l == 2 ? b2 : b3));
    bp[idx] = b[et * 128 + permf(s)];
    return;
  }
  idx -= 1024;
  if (idx < 384) {  // embed pi-order bf16
    int v = idx >> 7, s = idx & 127;
    embp[idx] = f2bf(embed[v * 128 + permf(s)]);
    return;
  }
  idx -= 384;
  if (idx < 128) swp[idx] = sw[permf(idx)];
}

// ---------------- init: x = embed[q] (pi, bf16), h = x, rc = 0 ----------------
__global__ void init_kernel(const int* __restrict__ q, const u16* __restrict__ embp,
                            u16* __restrict__ xb, u16* __restrict__ h, float* __restrict__ rc)
{
  int idx = blockIdx.x * 256 + threadIdx.x;
  int c = idx >> 7, s = idx & 127;
  u16 v = embp[q[c] * 128 + s];
  xb[idx] = v;
  h[idx] = v;
  rc[idx] = 0.f;
}

// bias + relu + pack-transpose into swizzled per-wave LDS A-tile (pitch 128, 8-col XOR swizzle)
__device__ __forceinline__ void bias_relu_store(f32x4 (&acc)[4][8], const float* __restrict__ bl,
                                                u16* __restrict__ ab, int q, int c)
{
  float bias[8];
  #pragma unroll
  for (int j = 0; j < 8; ++j) bias[j] = bl[c * 8 + j];
  #pragma unroll
  for (int mt = 0; mt < 4; ++mt) {
    #pragma unroll
    for (int r = 0; r < 4; ++r) {
      const int rowl = mt * 16 + 4 * q + r;
      short8 t;
      #pragma unroll
      for (int nt = 0; nt < 8; ++nt) {
        float v = acc[mt][nt][r] + bias[nt];
        v = v > 0.f ? v : 0.f;
        t[nt] = (short)f2bf(v);
      }
      *(short8*)(ab + rowl * 128 + ((c ^ (rowl & 15)) << 3)) = t;
    }
  }
}

// ---------------- fused 4-layer edge MLP + scatter-add ----------------
// block: 4 waves x 64 edges; grid.y = edge type
__launch_bounds__(256, 2)
__global__ void msg_kernel(
    const u16* __restrict__ h,
    const int* __restrict__ esrc, const int* __restrict__ edst,
    const u16* __restrict__ W0b, const u16* __restrict__ W1b,
    const u16* __restrict__ W2b, const u16* __restrict__ W3b,
    const float* __restrict__ bp,
    float* __restrict__ m0, float* __restrict__ m1)
{
  __shared__ u16 abuf[4][64 * 128];  // 64KB, per-wave private, XOR-swizzled
  const int et = blockIdx.y;
  const int tid = threadIdx.x;
  const int w = tid >> 6, lane = tid & 63, q = lane >> 4, c = lane & 15;
  const int ebase = blockIdx.x * 256 + w * 64;
  const int* __restrict__ src = esrc + et * NE;
  const int* __restrict__ dst = edst + et * NE;
  const u16* __restrict__ Wl0 = W0b + et * 32768;
  const u16* __restrict__ Wl[3] = {W1b + et * 16384, W2b + et * 16384, W3b + et * 16384};
  float* __restrict__ msgs = (et == 0) ? m0 : m1;
  u16* ab = abuf[w];

  int rowS[4], rowD[4];
  #pragma unroll
  for (int mt = 0; mt < 4; ++mt) {
    int e = ebase + mt * 16 + c;
    if (e >= NE) e = NE - 1;
    rowS[mt] = src[e];
    rowD[mt] = dst[e];
  }

  const f32x4 zf = {0.f, 0.f, 0.f, 0.f};
  f32x4 acc[4][8];
  #pragma unroll
  for (int mt = 0; mt < 4; ++mt)
    #pragma unroll
    for (int nt = 0; nt < 8; ++nt) acc[mt][nt] = zf;

  // layer 0: K=256 = [h[src] | h[dst]], A gathered straight from global h (16B/lane)
  #pragma unroll
  for (int ks = 0; ks < 8; ++ks) {
    const int kq = ks * 32 + q * 8;
    short8 a[4], b[8];
    #pragma unroll
    for (int mt = 0; mt < 4; ++mt) {
      int row = (ks < 4) ? rowS[mt] : rowD[mt];
      a[mt] = *(const short8*)(h + row * HID + (kq & 127));
    }
    #pragma unroll
    for (int nt = 0; nt < 8; ++nt)
      b[nt] = *(const short8*)(Wl0 + (nt * 16 + c) * 256 + kq);
    #pragma unroll
    for (int mt = 0; mt < 4; ++mt)
      #pragma unroll
      for (int nt = 0; nt < 8; ++nt)
        acc[mt][nt] = __builtin_amdgcn_mfma_f32_16x16x32_bf16(a[mt], b[nt], acc[mt][nt], 0, 0, 0);
  }
  bias_relu_store(acc, bp + et * 128, ab, q, c);

  // layers 1..3 (wave-private LDS round-trip; in-order DS => no barriers)
  #pragma unroll
  for (int l = 0; l < 3; ++l) {
    #pragma unroll
    for (int mt = 0; mt < 4; ++mt)
      #pragma unroll
      for (int nt = 0; nt < 8; ++nt) acc[mt][nt] = zf;
    #pragma unroll
    for (int ks = 0; ks < 4; ++ks) {
      const int kq = ks * 32 + q * 8;
      const int blk = ks * 4 + q;
      short8 a[4], b[8];
      #pragma unroll
      for (int mt = 0; mt < 4; ++mt) {
        const int row = mt * 16 + c;
        a[mt] = *(const short8*)(ab + row * 128 + ((blk ^ c) << 3));
      }
      #pragma unroll
      for (int nt = 0; nt < 8; ++nt)
        b[nt] = *(const short8*)(Wl[l] + (nt * 16 + c) * 128 + kq);
      #pragma unroll
      for (int mt = 0; mt < 4; ++mt)
        #pragma unroll
        for (int nt = 0; nt < 8; ++nt)
          acc[mt][nt] = __builtin_amdgcn_mfma_f32_16x16x32_bf16(a[mt], b[nt], acc[mt][nt], 0, 0, 0);
    }
    if (l < 2) {
      bias_relu_store(acc, bp + (l + 1) * 256 + et * 128, ab, q, c);
    } else {
      // layer-3 epilogue: +bias, fp32 atomic segment-sum into pi-ordered m (8 consecutive floats/lane)
      float bias[8];
      #pragma unroll
      for (int j = 0; j < 8; ++j) bias[j] = bp[3 * 256 + et * 128 + c * 8 + j];
      #pragma unroll
      for (int mt = 0; mt < 4; ++mt) {
        #pragma unroll
        for (int r = 0; r < 4; ++r) {
          int e = ebase + mt * 16 + 4 * q + r;
          if (e < NE) {
            int d = dst[e];
            float* mp = msgs + d * HID + c * 8;
            #pragma unroll
            for (int nt = 0; nt < 8; ++nt)
              atomicAdd(mp + nt, acc[mt][nt][r] + bias[nt]);
          }
        }
      }
    }
  }
}

// ---------------- fused LSTM: gates GEMM (K=512) + activations + score ----------------
// block: 4 waves, 64 cells, full 512 gates (wave w = gate quarter w)
__launch_bounds__(256, 2)
__global__ void lstm_kernel(
    const int step,
    const u16* __restrict__ xb, const float* __restrict__ mm0, const float* __restrict__ mm1,
    u16* __restrict__ h, float* __restrict__ rc,
    const u16* __restrict__ Wcb, const float* __restrict__ swp,
    float* __restrict__ out)
{
  __shared__ u16 at[64 * 512];  // 64KB swizzled: A-tile, then reused for gates exchange
  const int tid = threadIdx.x;
  const int cb = blockIdx.x * 64;

  // stage A = [x | m0 | m1 | rh] as bf16 (rh = 0 at step 0)
  for (int base = tid * 8; base < 64 * 512; base += 2048) {
    const int cl = base >> 9, s = base & 511;
    const int cell = cb + cl;
    short8 t;
    if (s < 128) {
      t = *(const short8*)(xb + cell * 128 + s);
    } else if (s < 384) {
      const float* mp = (s < 256 ? mm0 : mm1) + cell * 128 + (s & 127);
      #pragma unroll
      for (int j = 0; j < 8; ++j) t[j] = (short)f2bf(mp[j]);
    } else if (step == 0) {
      #pragma unroll
      for (int j = 0; j < 8; ++j) t[j] = 0;
    } else {
      t = *(const short8*)(h + cell * 128 + (s & 127));
    }
    const int blk = s >> 3;
    const int blks = (blk & 48) | ((blk ^ cl) & 15);
    *(short8*)(at + cl * 512 + blks * 8) = t;
  }
  __syncthreads();

  const int w = tid >> 6, lane = tid & 63, q = lane >> 4, c = lane & 15;
  const f32x4 zf = {0.f, 0.f, 0.f, 0.f};
  f32x4 acc[4][8];
  #pragma unroll
  for (int mt = 0; mt < 4; ++mt)
    #pragma unroll
    for (int nt = 0; nt < 8; ++nt) acc[mt][nt] = zf;

  #pragma unroll
  for (int ks = 0; ks < 16; ++ks) {
    const int kq = ks * 32 + q * 8;
    const int blk = (kq >> 3);  // 0..63
    short8 a[4], b[8];
    #pragma unroll
    for (int mt = 0; mt < 4; ++mt) {
      const int row = mt * 16 + c;
      const int blks = (blk & 48) | ((blk ^ c) & 15);
      a[mt] = *(const short8*)(at + row * 512 + blks * 8);
    }
    #pragma unroll
    for (int nt = 0; nt < 8; ++nt)
      b[nt] = *(const short8*)(Wcb + (w * 128 + nt * 16 + c) * 512 + kq);
    #pragma unroll
    for (int mt = 0; mt < 4; ++mt)
      #pragma unroll
      for (int nt = 0; nt < 8; ++nt)
        acc[mt][nt] = __builtin_amdgcn_mfma_f32_16x16x32_bf16(a[mt], b[nt], acc[mt][nt], 0, 0, 0);
  }
  __syncthreads();

  // exchange gates through LDS (bf16, same swizzle)
  #pragma unroll
  for (int mt = 0; mt < 4; ++mt) {
    #pragma unroll
    for (int r = 0; r < 4; ++r) {
      const int rowl = mt * 16 + 4 * q + r;
      short8 t;
      #pragma unroll
      for (int nt = 0; nt < 8; ++nt) t[nt] = (short)f2bf(acc[mt][nt][r]);
      const int blks = (w << 4) | ((c ^ (rowl & 15)) & 15);
      *(short8*)(at + rowl * 512 + blks * 8) = t;
    }
  }
  __syncthreads();

  // epilogue: lane (w,q,c) -> cell w*16+c, feature chunk q*32..q*32+31 (stored order)
  const int cl = w * 16 + c;
  const int cell = cb + cl;
  float* rcp = rc + cell * 128 + q * 32;
  u16* hp = h + cell * 128 + q * 32;
  const float* swq = swp + q * 32;
  float lsum = 0.f;
  #pragma unroll
  for (int jj = 0; jj < 32; jj += 8) {
    const int bq = q * 4 + (jj >> 3);  // within-quarter block 0..15
    const int bx = (bq ^ cl) & 15;
    short8 iv = *(const short8*)(at + cl * 512 + ((0 << 4) | bx) * 8 + 0);
    short8 fv = *(const short8*)(at + cl * 512 + ((1 << 4) | bx) * 8);
    short8 gv = *(const short8*)(at + cl * 512 + ((2 << 4) | bx) * 8);
    short8 ov = *(const short8*)(at + cl * 512 + ((3 << 4) | bx) * 8);
    short8 nh8;
    #pragma unroll
    for (int j = 0; j < 8; ++j) {
      float ig = sigm(bf2f((u16)iv[j]));
      float fg = sigm(bf2f((u16)fv[j]));
      float gg = tanha(bf2f((u16)gv[j]));
      float og = sigm(bf2f((u16)ov[j]));
      float c0 = rcp[jj + j];
      float nc = fg * c0 + ig * gg;
      float nhv = og * tanha(nc);
      rcp[jj + j] = nc;
      nh8[j] = (short)f2bf(nhv);
      lsum += nhv * swq[jj + j];
    }
    *(short8*)(hp + jj) = nh8;
  }
  lsum += __shfl_xor(lsum, 16);
  lsum += __shfl_xor(lsum, 32);
  if (q == 0) out[step * CELLS + cell] = lsum;
}

extern "C" void kernel_launch(void* const* d_in, const int* in_sizes, int n_in,
                              void* d_out, int out_size, void* d_ws, size_t ws_size,
                              hipStream_t stream)
{
  const int* q      = (const int*)d_in[0];
  const int* esrc   = (const int*)d_in[1];
  const int* edst   = (const int*)d_in[2];
  const float* embed= (const float*)d_in[3];
  const float* W0   = (const float*)d_in[4];
  const float* b0   = (const float*)d_in[5];
  const float* W1   = (const float*)d_in[6];
  const float* b1   = (const float*)d_in[7];
  const float* W2   = (const float*)d_in[8];
  const float* b2   = (const float*)d_in[9];
  const float* W3   = (const float*)d_in[10];
  const float* b3   = (const float*)d_in[11];
  const float* Wih  = (const float*)d_in[12];
  const float* Whh  = (const float*)d_in[13];
  const float* sw   = (const float*)d_in[14];

  char* ws = (char*)d_ws;
  size_t off = 0;
  auto alloc = [&](size_t bytes) {
    void* p = ws + off;
    off += (bytes + 255) & ~(size_t)255;
    return p;
  };
  u16*   h    = (u16*)  alloc((size_t)CELLS * HID * 2);
  u16*   xb   = (u16*)  alloc((size_t)CELLS * HID * 2);
  float* rc   = (float*)alloc((size_t)CELLS * HID * 4);
  float* m0   = (float*)alloc((size_t)CELLS * HID * 4);
  float* m1   = (float*)alloc((size_t)CELLS * HID * 4);
  u16*   W0b  = (u16*)  alloc(2 * 128 * 256 * 2);
  u16*   W1b  = (u16*)  alloc(2 * 128 * 128 * 2);
  u16*   W2b  = (u16*)  alloc(2 * 128 * 128 * 2);
  u16*   W3b  = (u16*)  alloc(2 * 128 * 128 * 2);
  u16*   Wcb  = (u16*)  alloc(512 * 512 * 2);
  float* bp   = (float*)alloc(4 * 256 * 4);
  u16*   embp = (u16*)  alloc(384 * 2);
  float* swp  = (float*)alloc(128 * 4);

  prep_kernel<<<1670, 256, 0, stream>>>(W0, W1, W2, W3, b0, b1, b2, b3, Wih, Whh, embed, sw,
                                        W0b, W1b, W2b, W3b, Wcb, bp, embp, swp);
  init_kernel<<<(CELLS * HID) / 256, 256, 0, stream>>>(q, embp, xb, h, rc);

  for (int step = 0; step < NSTEPS; ++step) {
    hipMemsetAsync(m0, 0, (size_t)CELLS * HID * 4, stream);
    hipMemsetAsync(m1, 0, (size_t)CELLS * HID * 4, stream);
    msg_kernel<<<dim3((NE + 255) / 256, 2), 256, 0, stream>>>(h, esrc, edst, W0b, W1b, W2b, W3b,
                                                              bp, m0, m1);
    lstm_kernel<<<CELLS / 64, 256, 0, stream>>>(step, xb, m0, m1, h, rc, Wcb, swp, (float*)d_out);
  }
}

// Round 2
// 1100.925 us; speedup vs baseline: 3.7488x; 3.7488x over previous
//
#include <hip/hip_runtime.h>

#define HID 128
#define CELLS 98304
#define NE 250000
#define NSTEPS 2

typedef __attribute__((ext_vector_type(8))) short short8;
typedef __attribute__((ext_vector_type(4))) float f32x4;
typedef unsigned short u16;

// pi permutation: stored slot s holds natural feature perm(s)
__device__ __forceinline__ int permf(int s) { return ((s & 7) << 4) | (s >> 3); }

__device__ __forceinline__ u16 f2bf(float f) {
  unsigned int u = __builtin_bit_cast(unsigned int, f);
  u += 0x7fffu + ((u >> 16) & 1u);
  return (u16)(u >> 16);
}
__device__ __forceinline__ float bf2f(u16 s) {
  unsigned int u = ((unsigned int)s) << 16;
  return __builtin_bit_cast(float, u);
}
__device__ __forceinline__ float sigm(float x) { return 1.f / (1.f + __expf(-x)); }
__device__ __forceinline__ float tanha(float x) { return 1.f - 2.f / (__expf(2.f * x) + 1.f); }

// ---------------- prep: bf16-convert + pi-permute all weights ----------------
__global__ void prep_kernel(
    const float* __restrict__ W0, const float* __restrict__ W1,
    const float* __restrict__ W2, const float* __restrict__ W3,
    const float* __restrict__ b0, const float* __restrict__ b1,
    const float* __restrict__ b2, const float* __restrict__ b3,
    const float* __restrict__ Wih, const float* __restrict__ Whh,
    const float* __restrict__ embed, const float* __restrict__ sw,
    u16* __restrict__ W0b, u16* __restrict__ W1b,
    u16* __restrict__ W2b, u16* __restrict__ W3b,
    u16* __restrict__ Wcb, float* __restrict__ bp,
    u16* __restrict__ embp, float* __restrict__ swp)
{
  int idx = blockIdx.x * 256 + threadIdx.x;
  if (idx < 65536) {  // W0b [et][n][s], s in [0,256): k_nat = perm on each 128-half
    int s = idx & 255, n = (idx >> 8) & 127, et = idx >> 15;
    int k = (s < 128) ? permf(s) : (128 + permf(s & 127));
    W0b[idx] = f2bf(W0[(et * 128 + n) * 256 + k]);
    return;
  }
  idx -= 65536;
  if (idx < 98304) {  // W1b/W2b/W3b [et][n][s]
    int which = idx >> 15, r = idx & 32767;
    int s = r & 127, n = (r >> 7) & 127, et = r >> 14;
    const float* W = which == 0 ? W1 : (which == 1 ? W2 : W3);
    u16* Wb = which == 0 ? W1b : (which == 1 ? W2b : W3b);
    Wb[r] = f2bf(W[(et * 128 + n) * 128 + permf(s)]);
    return;
  }
  idx -= 98304;
  if (idx < 262144) {  // Wcat [n=512][s=512] = [Wih(x|m0|m1) | Whh], per-128-block perm
    int s = idx & 511, n = idx >> 9;
    int blk = s >> 7, s7 = s & 127;
    float v = (blk < 3) ? Wih[n * 384 + blk * 128 + permf(s7)] : Whh[n * 128 + permf(s7)];
    Wcb[idx] = f2bf(v);
    return;
  }
  idx -= 262144;
  if (idx < 1024) {  // biases [layer 0..3][et][s] pi-order
    int l = idx >> 8, r = idx & 255;
    int et = r >> 7, s = r & 127;
    const float* b = l == 0 ? b0 : (l == 1 ? b1 : (l == 2 ? b2 : b3));
    bp[idx] = b[et * 128 + permf(s)];
    return;
  }
  idx -= 1024;
  if (idx < 384) {  // embed pi-order bf16
    int v = idx >> 7, s = idx & 127;
    embp[idx] = f2bf(embed[v * 128 + permf(s)]);
    return;
  }
  idx -= 384;
  if (idx < 128) swp[idx] = sw[permf(idx)];
}

// ---------------- init: x = embed[q] (pi, bf16), h = x, rc = 0 ----------------
__global__ void init_kernel(const int* __restrict__ q, const u16* __restrict__ embp,
                            u16* __restrict__ xb, u16* __restrict__ h, float* __restrict__ rc)
{
  int idx = blockIdx.x * 256 + threadIdx.x;
  int c = idx >> 7, s = idx & 127;
  u16 v = embp[q[c] * 128 + s];
  xb[idx] = v;
  h[idx] = v;
  rc[idx] = 0.f;
}

// ---------------- dst-sort pipeline: hist -> scan (2-level) -> scatter ----------------
__global__ void hist_kernel(const int* __restrict__ edst, int* __restrict__ counts)
{
  int idx = blockIdx.x * 256 + threadIdx.x;
  if (idx >= 2 * NE) return;
  int et = (idx >= NE) ? 1 : 0;
  atomicAdd(&counts[et * CELLS + edst[idx]], 1);
}

__global__ void scan1_kernel(const int* __restrict__ counts, int* __restrict__ S,
                             int* __restrict__ btot)
{
  __shared__ int sh[1024];
  const int t = threadIdx.x, b = blockIdx.x;
  const int i = b * 1024 + t;
  int v = counts[i];
  sh[t] = v;
  __syncthreads();
  int acc = v;
  for (int off = 1; off < 1024; off <<= 1) {
    int add = (t >= off) ? sh[t - off] : 0;
    __syncthreads();
    acc += add;
    sh[t] = acc;
    __syncthreads();
  }
  S[i] = acc - v;  // block-local exclusive
  if (t == 1023) btot[b] = acc;
}

__global__ void scan2_kernel(const int* __restrict__ btot, int* __restrict__ boffs,
                             int* __restrict__ S)
{
  __shared__ int sh[256];
  const int t = threadIdx.x;
  int v = (t < 192) ? btot[t] : 0;
  sh[t] = v;
  __syncthreads();
  int acc = v;
  for (int off = 1; off < 256; off <<= 1) {
    int add = (t >= off) ? sh[t - off] : 0;
    __syncthreads();
    acc += add;
    sh[t] = acc;
    __syncthreads();
  }
  if (t < 192) boffs[t] = acc - v;
  if (t == 0) S[2 * CELLS] = 2 * NE;
}

__global__ void scan3_kernel(int* __restrict__ S, const int* __restrict__ boffs)
{
  const int i = blockIdx.x * 1024 + threadIdx.x;
  S[i] += boffs[blockIdx.x];
}

__global__ void scatter_kernel(const int* __restrict__ esrc, const int* __restrict__ edst,
                               const int* __restrict__ S, int* __restrict__ fill,
                               int* __restrict__ ssrc, int* __restrict__ sdst)
{
  int idx = blockIdx.x * 256 + threadIdx.x;
  if (idx >= 2 * NE) return;
  int et = (idx >= NE) ? 1 : 0;
  int d = edst[idx];
  int pos = atomicAdd(&fill[et * CELLS + d], 1);
  int slot = S[et * CELLS + d] - et * NE + pos;  // et-local sorted slot
  sdst[et * NE + slot] = d;
  ssrc[et * NE + slot] = esrc[idx];
}

// bias + relu + pack-transpose into swizzled per-wave LDS A-tile (pitch 128, 8-col XOR swizzle)
__device__ __forceinline__ void bias_relu_store(f32x4 (&acc)[4][8], const float* __restrict__ bl,
                                                u16* __restrict__ ab, int q, int c)
{
  float bias[8];
  #pragma unroll
  for (int j = 0; j < 8; ++j) bias[j] = bl[c * 8 + j];
  #pragma unroll
  for (int mt = 0; mt < 4; ++mt) {
    #pragma unroll
    for (int r = 0; r < 4; ++r) {
      const int rowl = mt * 16 + 4 * q + r;
      short8 t;
      #pragma unroll
      for (int nt = 0; nt < 8; ++nt) {
        float v = acc[mt][nt][r] + bias[nt];
        v = v > 0.f ? v : 0.f;
        t[nt] = (short)f2bf(v);
      }
      *(short8*)(ab + rowl * 128 + ((c ^ (rowl & 15)) << 3)) = t;
    }
  }
}

// ---------------- fused 4-layer edge MLP + sorted segmented-sum scatter ----------------
// block: 4 waves x 64 edges (dst-sorted); grid.y = edge type
__launch_bounds__(256, 2)
__global__ void msg_kernel(
    const u16* __restrict__ h,
    const int* __restrict__ ssrc, const int* __restrict__ sdst,
    const int* __restrict__ S,
    const u16* __restrict__ W0b, const u16* __restrict__ W1b,
    const u16* __restrict__ W2b, const u16* __restrict__ W3b,
    const float* __restrict__ bp,
    float* __restrict__ m0, float* __restrict__ m1)
{
  __shared__ u16 abuf[4][64 * 128];  // 64KB, per-wave private, XOR-swizzled
  const int et = blockIdx.y;
  const int tid = threadIdx.x;
  const int w = tid >> 6, lane = tid & 63, q = lane >> 4, c = lane & 15;
  const int ebase = blockIdx.x * 256 + w * 64;  // et-local sorted slot base for this wave
  const int* __restrict__ src = ssrc + et * NE;
  const int* __restrict__ dst = sdst + et * NE;
  const u16* __restrict__ Wl0 = W0b + et * 32768;
  const u16* __restrict__ Wl[3] = {W1b + et * 16384, W2b + et * 16384, W3b + et * 16384};
  float* __restrict__ msgs = (et == 0) ? m0 : m1;
  u16* ab = abuf[w];

  int rowS[4], rowD[4];
  #pragma unroll
  for (int mt = 0; mt < 4; ++mt) {
    int e = ebase + mt * 16 + c;
    if (e >= NE) e = NE - 1;
    rowS[mt] = src[e];
    rowD[mt] = dst[e];
  }

  // per-lane row metadata for the segmented epilogue: this lane owns row `lane`
  const int eL = ebase + lane;
  const int dval = (eL < NE) ? dst[eL] : -1;
  int rpS = 0, rpE = 0;
  if (dval >= 0) {
    rpS = S[et * CELLS + dval] - et * NE;
    rpE = S[et * CELLS + dval + 1] - et * NE;
  }

  const f32x4 zf = {0.f, 0.f, 0.f, 0.f};
  f32x4 acc[4][8];
  #pragma unroll
  for (int mt = 0; mt < 4; ++mt)
    #pragma unroll
    for (int nt = 0; nt < 8; ++nt) acc[mt][nt] = zf;

  // layer 0: K=256 = [h[src] | h[dst]], A gathered straight from global h (16B/lane)
  #pragma unroll
  for (int ks = 0; ks < 8; ++ks) {
    const int kq = ks * 32 + q * 8;
    short8 a[4], b[8];
    #pragma unroll
    for (int mt = 0; mt < 4; ++mt) {
      int row = (ks < 4) ? rowS[mt] : rowD[mt];
      a[mt] = *(const short8*)(h + row * HID + (kq & 127));
    }
    #pragma unroll
    for (int nt = 0; nt < 8; ++nt)
      b[nt] = *(const short8*)(Wl0 + (nt * 16 + c) * 256 + kq);
    #pragma unroll
    for (int mt = 0; mt < 4; ++mt)
      #pragma unroll
      for (int nt = 0; nt < 8; ++nt)
        acc[mt][nt] = __builtin_amdgcn_mfma_f32_16x16x32_bf16(a[mt], b[nt], acc[mt][nt], 0, 0, 0);
  }
  bias_relu_store(acc, bp + et * 128, ab, q, c);

  // layers 1..3 (wave-private LDS round-trip; in-order DS => no barriers)
  #pragma unroll
  for (int l = 0; l < 3; ++l) {
    #pragma unroll
    for (int mt = 0; mt < 4; ++mt)
      #pragma unroll
      for (int nt = 0; nt < 8; ++nt) acc[mt][nt] = zf;
    #pragma unroll
    for (int ks = 0; ks < 4; ++ks) {
      const int kq = ks * 32 + q * 8;
      const int blk = ks * 4 + q;
      short8 a[4], b[8];
      #pragma unroll
      for (int mt = 0; mt < 4; ++mt) {
        const int row = mt * 16 + c;
        a[mt] = *(const short8*)(ab + row * 128 + ((blk ^ c) << 3));
      }
      #pragma unroll
      for (int nt = 0; nt < 8; ++nt)
        b[nt] = *(const short8*)(Wl[l] + (nt * 16 + c) * 128 + kq);
      #pragma unroll
      for (int mt = 0; mt < 4; ++mt)
        #pragma unroll
        for (int nt = 0; nt < 8; ++nt)
          acc[mt][nt] = __builtin_amdgcn_mfma_f32_16x16x32_bf16(a[mt], b[nt], acc[mt][nt], 0, 0, 0);
    }
    if (l < 2) bias_relu_store(acc, bp + (l + 1) * 256 + et * 128, ab, q, c);
  }

  // layer-3 epilogue: +bias, LDS fp32 transpose (two 64-feature passes), run-length
  // segmented sum over sorted dst, plain store for wave-interior cells, atomic at borders.
  float bias[8];
  #pragma unroll
  for (int j = 0; j < 8; ++j) bias[j] = bp[3 * 256 + et * 128 + c * 8 + j];

  float* fab = (float*)ab;  // 64 rows x 64 feature-slots fp32 (16KB, wave-private)
  #pragma unroll
  for (int half = 0; half < 2; ++half) {
    #pragma unroll
    for (int mt = 0; mt < 4; ++mt) {
      #pragma unroll
      for (int r = 0; r < 4; ++r) {
        const int row = mt * 16 + 4 * q + r;
        f32x4 t;
        #pragma unroll
        for (int nti = 0; nti < 4; ++nti)
          t[nti] = acc[mt][half * 4 + nti][r] + bias[half * 4 + nti];
        *(f32x4*)(fab + row * 64 + c * 4) = t;
      }
    }
    // stored pi-slot this lane handles in this pass
    const int sidx = ((lane >> 2) << 3) + (lane & 3) + half * 4;

    float run = 0.f;
    int dprev = -2, jstart = 0;
    for (int j = 0; j < 64; ++j) {
      int d = __shfl(dval, j);
      if (d != dprev) {  // wave-uniform
        if (dprev >= 0) {
          int rp0 = __shfl(rpS, jstart);
          int rp1 = __shfl(rpE, jstart);
          float* mp = msgs + (size_t)dprev * HID + sidx;
          if (rp0 >= ebase && rp1 <= ebase + 64) *mp = run;
          else atomicAdd(mp, run);
        }
        run = 0.f;
        dprev = d;
        jstart = j;
      }
      run += fab[j * 64 + lane];
    }
    if (dprev >= 0) {
      int rp0 = __shfl(rpS, jstart);
      int rp1 = __shfl(rpE, jstart);
      float* mp = msgs + (size_t)dprev * HID + sidx;
      if (rp0 >= ebase && rp1 <= ebase + 64) *mp = run;
      else atomicAdd(mp, run);
    }
  }
}

// ---------------- fused LSTM: gates GEMM (K=512) + activations + score ----------------
// block: 4 waves, 64 cells, full 512 gates (wave w = gate quarter w)
__launch_bounds__(256, 2)
__global__ void lstm_kernel(
    const int step,
    const u16* __restrict__ xb, const float* __restrict__ mm0, const float* __restrict__ mm1,
    u16* __restrict__ h, float* __restrict__ rc,
    const u16* __restrict__ Wcb, const float* __restrict__ swp,
    float* __restrict__ out)
{
  __shared__ u16 at[64 * 512];  // 64KB swizzled: A-tile, then reused for gates exchange
  const int tid = threadIdx.x;
  const int cb = blockIdx.x * 64;

  // stage A = [x | m0 | m1 | rh] as bf16 (rh = 0 at step 0)
  for (int base = tid * 8; base < 64 * 512; base += 2048) {
    const int cl = base >> 9, s = base & 511;
    const int cell = cb + cl;
    short8 t;
    if (s < 128) {
      t = *(const short8*)(xb + cell * 128 + s);
    } else if (s < 384) {
      const float* mp = (s < 256 ? mm0 : mm1) + cell * 128 + (s & 127);
      #pragma unroll
      for (int j = 0; j < 8; ++j) t[j] = (short)f2bf(mp[j]);
    } else if (step == 0) {
      #pragma unroll
      for (int j = 0; j < 8; ++j) t[j] = 0;
    } else {
      t = *(const short8*)(h + cell * 128 + (s & 127));
    }
    const int blk = s >> 3;
    const int blks = (blk & 48) | ((blk ^ cl) & 15);
    *(short8*)(at + cl * 512 + blks * 8) = t;
  }
  __syncthreads();

  const int w = tid >> 6, lane = tid & 63, q = lane >> 4, c = lane & 15;
  const f32x4 zf = {0.f, 0.f, 0.f, 0.f};
  f32x4 acc[4][8];
  #pragma unroll
  for (int mt = 0; mt < 4; ++mt)
    #pragma unroll
    for (int nt = 0; nt < 8; ++nt) acc[mt][nt] = zf;

  #pragma unroll
  for (int ks = 0; ks < 16; ++ks) {
    const int kq = ks * 32 + q * 8;
    const int blk = (kq >> 3);  // 0..63
    short8 a[4], b[8];
    #pragma unroll
    for (int mt = 0; mt < 4; ++mt) {
      const int row = mt * 16 + c;
      const int blks = (blk & 48) | ((blk ^ c) & 15);
      a[mt] = *(const short8*)(at + row * 512 + blks * 8);
    }
    #pragma unroll
    for (int nt = 0; nt < 8; ++nt)
      b[nt] = *(const short8*)(Wcb + (w * 128 + nt * 16 + c) * 512 + kq);
    #pragma unroll
    for (int mt = 0; mt < 4; ++mt)
      #pragma unroll
      for (int nt = 0; nt < 8; ++nt)
        acc[mt][nt] = __builtin_amdgcn_mfma_f32_16x16x32_bf16(a[mt], b[nt], acc[mt][nt], 0, 0, 0);
  }
  __syncthreads();

  // exchange gates through LDS (bf16, same swizzle)
  #pragma unroll
  for (int mt = 0; mt < 4; ++mt) {
    #pragma unroll
    for (int r = 0; r < 4; ++r) {
      const int rowl = mt * 16 + 4 * q + r;
      short8 t;
      #pragma unroll
      for (int nt = 0; nt < 8; ++nt) t[nt] = (short)f2bf(acc[mt][nt][r]);
      const int blks = (w << 4) | ((c ^ (rowl & 15)) & 15);
      *(short8*)(at + rowl * 512 + blks * 8) = t;
    }
  }
  __syncthreads();

  // epilogue: lane (w,q,c) -> cell w*16+c, feature chunk q*32..q*32+31 (stored order)
  const int cl = w * 16 + c;
  const int cell = cb + cl;
  float* rcp = rc + cell * 128 + q * 32;
  u16* hp = h + cell * 128 + q * 32;
  const float* swq = swp + q * 32;
  float lsum = 0.f;
  #pragma unroll
  for (int jj = 0; jj < 32; jj += 8) {
    const int bq = q * 4 + (jj >> 3);  // within-quarter block 0..15
    const int bx = (bq ^ cl) & 15;
    short8 iv = *(const short8*)(at + cl * 512 + ((0 << 4) | bx) * 8 + 0);
    short8 fv = *(const short8*)(at + cl * 512 + ((1 << 4) | bx) * 8);
    short8 gv = *(const short8*)(at + cl * 512 + ((2 << 4) | bx) * 8);
    short8 ov = *(const short8*)(at + cl * 512 + ((3 << 4) | bx) * 8);
    short8 nh8;
    #pragma unroll
    for (int j = 0; j < 8; ++j) {
      float ig = sigm(bf2f((u16)iv[j]));
      float fg = sigm(bf2f((u16)fv[j]));
      float gg = tanha(bf2f((u16)gv[j]));
      float og = sigm(bf2f((u16)ov[j]));
      float c0 = rcp[jj + j];
      float nc = fg * c0 + ig * gg;
      float nhv = og * tanha(nc);
      rcp[jj + j] = nc;
      nh8[j] = (short)f2bf(nhv);
      lsum += nhv * swq[jj + j];
    }
    *(short8*)(hp + jj) = nh8;
  }
  lsum += __shfl_xor(lsum, 16);
  lsum += __shfl_xor(lsum, 32);
  if (q == 0) out[step * CELLS + cell] = lsum;
}

extern "C" void kernel_launch(void* const* d_in, const int* in_sizes, int n_in,
                              void* d_out, int out_size, void* d_ws, size_t ws_size,
                              hipStream_t stream)
{
  const int* q      = (const int*)d_in[0];
  const int* esrc   = (const int*)d_in[1];
  const int* edst   = (const int*)d_in[2];
  const float* embed= (const float*)d_in[3];
  const float* W0   = (const float*)d_in[4];
  const float* b0   = (const float*)d_in[5];
  const float* W1   = (const float*)d_in[6];
  const float* b1   = (const float*)d_in[7];
  const float* W2   = (const float*)d_in[8];
  const float* b2   = (const float*)d_in[9];
  const float* W3   = (const float*)d_in[10];
  const float* b3   = (const float*)d_in[11];
  const float* Wih  = (const float*)d_in[12];
  const float* Whh  = (const float*)d_in[13];
  const float* sw   = (const float*)d_in[14];

  char* ws = (char*)d_ws;
  size_t off = 0;
  auto alloc = [&](size_t bytes) {
    void* p = ws + off;
    off += (bytes + 255) & ~(size_t)255;
    return p;
  };
  u16*   h    = (u16*)  alloc((size_t)CELLS * HID * 2);
  u16*   xb   = (u16*)  alloc((size_t)CELLS * HID * 2);
  float* rc   = (float*)alloc((size_t)CELLS * HID * 4);
  float* m0   = (float*)alloc((size_t)CELLS * HID * 4);
  float* m1   = (float*)alloc((size_t)CELLS * HID * 4);
  u16*   W0b  = (u16*)  alloc(2 * 128 * 256 * 2);
  u16*   W1b  = (u16*)  alloc(2 * 128 * 128 * 2);
  u16*   W2b  = (u16*)  alloc(2 * 128 * 128 * 2);
  u16*   W3b  = (u16*)  alloc(2 * 128 * 128 * 2);
  u16*   Wcb  = (u16*)  alloc(512 * 512 * 2);
  float* bp   = (float*)alloc(4 * 256 * 4);
  u16*   embp = (u16*)  alloc(384 * 2);
  float* swp  = (float*)alloc(128 * 4);
  // sort workspace
  int*   counts = (int*)alloc((size_t)2 * CELLS * 4);
  int*   Sarr   = (int*)alloc(((size_t)2 * CELLS + 1) * 4);
  int*   fill   = (int*)alloc((size_t)2 * CELLS * 4);
  int*   btot   = (int*)alloc(192 * 4);
  int*   boffs  = (int*)alloc(192 * 4);
  int*   ssrc   = (int*)alloc((size_t)2 * NE * 4);
  int*   sdst   = (int*)alloc((size_t)2 * NE * 4);

  prep_kernel<<<1670, 256, 0, stream>>>(W0, W1, W2, W3, b0, b1, b2, b3, Wih, Whh, embed, sw,
                                        W0b, W1b, W2b, W3b, Wcb, bp, embp, swp);
  init_kernel<<<(CELLS * HID) / 256, 256, 0, stream>>>(q, embp, xb, h, rc);

  // dst-sort both edge types
  hipMemsetAsync(counts, 0, (size_t)2 * CELLS * 4, stream);
  hipMemsetAsync(fill, 0, (size_t)2 * CELLS * 4, stream);
  hist_kernel<<<(2 * NE + 255) / 256, 256, 0, stream>>>(edst, counts);
  scan1_kernel<<<192, 1024, 0, stream>>>(counts, Sarr, btot);
  scan2_kernel<<<1, 256, 0, stream>>>(btot, boffs, Sarr);
  scan3_kernel<<<192, 1024, 0, stream>>>(Sarr, boffs);
  scatter_kernel<<<(2 * NE + 255) / 256, 256, 0, stream>>>(esrc, edst, Sarr, fill, ssrc, sdst);

  for (int step = 0; step < NSTEPS; ++step) {
    hipMemsetAsync(m0, 0, (size_t)CELLS * HID * 4, stream);
    hipMemsetAsync(m1, 0, (size_t)CELLS * HID * 4, stream);
    msg_kernel<<<dim3((NE + 255) / 256, 2), 256, 0, stream>>>(h, ssrc, sdst, Sarr,
                                                              W0b, W1b, W2b, W3b, bp, m0, m1);
    lstm_kernel<<<CELLS / 64, 256, 0, stream>>>(step, xb, m0, m1, h, rc, Wcb, swp, (float*)d_out);
  }
}

// Round 4
// 984.760 us; speedup vs baseline: 4.1911x; 1.1180x over previous
//
#include <hip/hip_runtime.h>

#define HID 128
#define CELLS 98304
#define NE 250000
#define NSTEPS 2

typedef __attribute__((ext_vector_type(8))) short short8;
typedef __attribute__((ext_vector_type(4))) float f32x4;
typedef unsigned short u16;

// pi permutation: stored slot s holds natural feature perm(s)
__device__ __forceinline__ int permf(int s) { return ((s & 7) << 4) | (s >> 3); }

__device__ __forceinline__ u16 f2bf(float f) {
  unsigned int u = __builtin_bit_cast(unsigned int, f);
  u += 0x7fffu + ((u >> 16) & 1u);
  return (u16)(u >> 16);
}
__device__ __forceinline__ float bf2f(u16 s) {
  unsigned int u = ((unsigned int)s) << 16;
  return __builtin_bit_cast(float, u);
}
__device__ __forceinline__ float sigm(float x) { return 1.f / (1.f + __expf(-x)); }
__device__ __forceinline__ float tanha(float x) { return 1.f - 2.f / (__expf(2.f * x) + 1.f); }

// ---------------- prep: bf16-convert + pi-permute all weights ----------------
__global__ void prep_kernel(
    const float* __restrict__ W0, const float* __restrict__ W1,
    const float* __restrict__ W2, const float* __restrict__ W3,
    const float* __restrict__ b0, const float* __restrict__ b1,
    const float* __restrict__ b2, const float* __restrict__ b3,
    const float* __restrict__ Wih, const float* __restrict__ Whh,
    const float* __restrict__ embed, const float* __restrict__ sw,
    u16* __restrict__ W0b, u16* __restrict__ W1b,
    u16* __restrict__ W2b, u16* __restrict__ W3b,
    u16* __restrict__ Wcb, float* __restrict__ bp,
    u16* __restrict__ embp, float* __restrict__ swp)
{
  int idx = blockIdx.x * 256 + threadIdx.x;
  if (idx < 65536) {  // W0b [et][n][s], s in [0,256): k_nat = perm on each 128-half
    int s = idx & 255, n = (idx >> 8) & 127, et = idx >> 15;
    int k = (s < 128) ? permf(s) : (128 + permf(s & 127));
    W0b[idx] = f2bf(W0[(et * 128 + n) * 256 + k]);
    return;
  }
  idx -= 65536;
  if (idx < 98304) {  // W1b/W2b/W3b [et][n][s]
    int which = idx >> 15, r = idx & 32767;
    int s = r & 127, n = (r >> 7) & 127, et = r >> 14;
    const float* W = which == 0 ? W1 : (which == 1 ? W2 : W3);
    u16* Wb = which == 0 ? W1b : (which == 1 ? W2b : W3b);
    Wb[r] = f2bf(W[(et * 128 + n) * 128 + permf(s)]);
    return;
  }
  idx -= 98304;
  if (idx < 262144) {  // Wcat [n=512][s=512] = [Wih(x|m0|m1) | Whh], per-128-block perm
    int s = idx & 511, n = idx >> 9;
    int blk = s >> 7, s7 = s & 127;
    float v = (blk < 3) ? Wih[n * 384 + blk * 128 + permf(s7)] : Whh[n * 128 + permf(s7)];
    Wcb[idx] = f2bf(v);
    return;
  }
  idx -= 262144;
  if (idx < 1024) {  // biases [layer 0..3][et][s] pi-order
    int l = idx >> 8, r = idx & 255;
    int et = r >> 7, s = r & 127;
    const float* b = l == 0 ? b0 : (l == 1 ? b1 : (l == 2 ? b2 : b3));
    bp[idx] = b[et * 128 + permf(s)];
    return;
  }
  idx -= 1024;
  if (idx < 384) {  // embed pi-order bf16
    int v = idx >> 7, s = idx & 127;
    embp[idx] = f2bf(embed[v * 128 + permf(s)]);
    return;
  }
  idx -= 384;
  if (idx < 128) swp[idx] = sw[permf(idx)];
}

// ---------------- init: x = embed[q] (pi, bf16), h = x, rc = 0 ----------------
__global__ void init_kernel(const int* __restrict__ q, const u16* __restrict__ embp,
                            u16* __restrict__ xb, u16* __restrict__ h, float* __restrict__ rc)
{
  int idx = blockIdx.x * 256 + threadIdx.x;
  int c = idx >> 7, s = idx & 127;
  u16 v = embp[q[c] * 128 + s];
  xb[idx] = v;
  h[idx] = v;
  rc[idx] = 0.f;
}

// ---------------- dst-sort pipeline: hist -> scan (2-level) -> scatter ----------------
__global__ void hist_kernel(const int* __restrict__ edst, int* __restrict__ counts)
{
  int idx = blockIdx.x * 256 + threadIdx.x;
  if (idx >= 2 * NE) return;
  int et = (idx >= NE) ? 1 : 0;
  atomicAdd(&counts[et * CELLS + edst[idx]], 1);
}

__global__ void scan1_kernel(const int* __restrict__ counts, int* __restrict__ S,
                             int* __restrict__ btot)
{
  __shared__ int sh[1024];
  const int t = threadIdx.x, b = blockIdx.x;
  const int i = b * 1024 + t;
  int v = counts[i];
  sh[t] = v;
  __syncthreads();
  int acc = v;
  for (int off = 1; off < 1024; off <<= 1) {
    int add = (t >= off) ? sh[t - off] : 0;
    __syncthreads();
    acc += add;
    sh[t] = acc;
    __syncthreads();
  }
  S[i] = acc - v;  // block-local exclusive
  if (t == 1023) btot[b] = acc;
}

__global__ void scan2_kernel(const int* __restrict__ btot, int* __restrict__ boffs,
                             int* __restrict__ S)
{
  __shared__ int sh[256];
  const int t = threadIdx.x;
  int v = (t < 192) ? btot[t] : 0;
  sh[t] = v;
  __syncthreads();
  int acc = v;
  for (int off = 1; off < 256; off <<= 1) {
    int add = (t >= off) ? sh[t - off] : 0;
    __syncthreads();
    acc += add;
    sh[t] = acc;
    __syncthreads();
  }
  if (t < 192) boffs[t] = acc - v;
  if (t == 0) S[2 * CELLS] = 2 * NE;
}

__global__ void scan3_kernel(int* __restrict__ S, const int* __restrict__ boffs)
{
  const int i = blockIdx.x * 1024 + threadIdx.x;
  S[i] += boffs[blockIdx.x];
}

__global__ void scatter_kernel(const int* __restrict__ esrc, const int* __restrict__ edst,
                               const int* __restrict__ S, int* __restrict__ fill,
                               int* __restrict__ ssrc, int* __restrict__ sdst)
{
  int idx = blockIdx.x * 256 + threadIdx.x;
  if (idx >= 2 * NE) return;
  int et = (idx >= NE) ? 1 : 0;
  int d = edst[idx];
  int pos = atomicAdd(&fill[et * CELLS + d], 1);
  int slot = S[et * CELLS + d] - et * NE + pos;  // et-local sorted slot
  sdst[et * NE + slot] = d;
  ssrc[et * NE + slot] = esrc[idx];
}

// bias + relu + pack-transpose into swizzled per-wave LDS A-tile (pitch 128, 8-col XOR swizzle)
__device__ __forceinline__ void bias_relu_store(f32x4 (&acc)[4][8], const float* __restrict__ bl,
                                                u16* __restrict__ ab, int q, int c)
{
  float bias[8];
  #pragma unroll
  for (int j = 0; j < 8; ++j) bias[j] = bl[c * 8 + j];
  #pragma unroll
  for (int mt = 0; mt < 4; ++mt) {
    #pragma unroll
    for (int r = 0; r < 4; ++r) {
      const int rowl = mt * 16 + 4 * q + r;
      short8 t;
      #pragma unroll
      for (int nt = 0; nt < 8; ++nt) {
        float v = acc[mt][nt][r] + bias[nt];
        v = v > 0.f ? v : 0.f;
        t[nt] = (short)f2bf(v);
      }
      *(short8*)(ab + rowl * 128 + ((c ^ (rowl & 15)) << 3)) = t;
    }
  }
}

// ---------------- fused 4-layer edge MLP + sorted segmented-sum scatter ----------------
// block: 2 waves x 64 edges (dst-sorted), 32KB LDS -> better occupancy; grid.y = edge type
// m layout ("epilogue order"): m[d][h*64 + l] = pi-slot (l>>2)*8 + 4h + (l&3)
__launch_bounds__(128, 2)
__global__ void msg_kernel(
    const u16* __restrict__ h,
    const int* __restrict__ ssrc, const int* __restrict__ sdst,
    const int* __restrict__ S,
    const u16* __restrict__ W0b, const u16* __restrict__ W1b,
    const u16* __restrict__ W2b, const u16* __restrict__ W3b,
    const float* __restrict__ bp,
    float* __restrict__ m0, float* __restrict__ m1)
{
  __shared__ u16 abuf[2][64 * 128];  // 32KB, per-wave private, XOR-swizzled
  const int et = blockIdx.y;
  const int tid = threadIdx.x;
  const int w = tid >> 6, lane = tid & 63, q = lane >> 4, c = lane & 15;
  const int ebase = blockIdx.x * 128 + w * 64;  // et-local sorted slot base for this wave
  const int* __restrict__ src = ssrc + et * NE;
  const int* __restrict__ dst = sdst + et * NE;
  const u16* __restrict__ Wl0 = W0b + et * 32768;
  const u16* __restrict__ Wl[3] = {W1b + et * 16384, W2b + et * 16384, W3b + et * 16384};
  float* __restrict__ msgs = (et == 0) ? m0 : m1;
  u16* ab = abuf[w];

  int rowS[4], rowD[4];
  #pragma unroll
  for (int mt = 0; mt < 4; ++mt) {
    int e = ebase + mt * 16 + c;
    if (e >= NE) e = NE - 1;
    rowS[mt] = src[e];
    rowD[mt] = dst[e];
  }

  // run structure for the segmented epilogue (computed once, wave-uniform masks).
  // NOTE: the shuffle MUST be unconditional — a cross-lane op inside a short-circuit
  // with divergent LHS reads from an exec-masked-off lane (undefined on CDNA). That
  // was round 3's bug: spurious run splits at lane 0 -> double plain-store clobber.
  const int eL = ebase + lane;
  const int dval = (eL < NE) ? dst[eL] : -1;
  int rpS = 0, rpE = 0;
  if (dval >= 0) {
    rpS = S[et * CELLS + dval] - et * NE;
    rpE = S[et * CELLS + dval + 1] - et * NE;
  }
  const int dlagged = __shfl_up(dval, 1);          // all 64 lanes active here
  const bool headp = (lane == 0) | (dval != dlagged);  // bitwise | : no control flow
  const unsigned long long tails = (__ballot(headp) >> 1) | (1ull << 63);
  const unsigned long long intmask = __ballot(dval >= 0 && rpS >= ebase && rpE <= ebase + 64);

  const f32x4 zf = {0.f, 0.f, 0.f, 0.f};
  f32x4 acc[4][8];
  #pragma unroll
  for (int mt = 0; mt < 4; ++mt)
    #pragma unroll
    for (int nt = 0; nt < 8; ++nt) acc[mt][nt] = zf;

  // layer 0: K=256 = [h[src] | h[dst]], A gathered straight from global h (16B/lane)
  #pragma unroll
  for (int ks = 0; ks < 8; ++ks) {
    const int kq = ks * 32 + q * 8;
    short8 a[4], b[8];
    #pragma unroll
    for (int mt = 0; mt < 4; ++mt) {
      int row = (ks < 4) ? rowS[mt] : rowD[mt];
      a[mt] = *(const short8*)(h + row * HID + (kq & 127));
    }
    #pragma unroll
    for (int nt = 0; nt < 8; ++nt)
      b[nt] = *(const short8*)(Wl0 + (nt * 16 + c) * 256 + kq);
    #pragma unroll
    for (int mt = 0; mt < 4; ++mt)
      #pragma unroll
      for (int nt = 0; nt < 8; ++nt)
        acc[mt][nt] = __builtin_amdgcn_mfma_f32_16x16x32_bf16(a[mt], b[nt], acc[mt][nt], 0, 0, 0);
  }
  bias_relu_store(acc, bp + et * 128, ab, q, c);

  // layers 1..3 (wave-private LDS round-trip; in-order DS => no barriers)
  #pragma unroll
  for (int l = 0; l < 3; ++l) {
    #pragma unroll
    for (int mt = 0; mt < 4; ++mt)
      #pragma unroll
      for (int nt = 0; nt < 8; ++nt) acc[mt][nt] = zf;
    #pragma unroll
    for (int ks = 0; ks < 4; ++ks) {
      const int kq = ks * 32 + q * 8;
      const int blk = ks * 4 + q;
      short8 a[4], b[8];
      #pragma unroll
      for (int mt = 0; mt < 4; ++mt) {
        const int row = mt * 16 + c;
        a[mt] = *(const short8*)(ab + row * 128 + ((blk ^ c) << 3));
      }
      #pragma unroll
      for (int nt = 0; nt < 8; ++nt)
        b[nt] = *(const short8*)(Wl[l] + (nt * 16 + c) * 128 + kq);
      #pragma unroll
      for (int mt = 0; mt < 4; ++mt)
        #pragma unroll
        for (int nt = 0; nt < 8; ++nt)
          acc[mt][nt] = __builtin_amdgcn_mfma_f32_16x16x32_bf16(a[mt], b[nt], acc[mt][nt], 0, 0, 0);
    }
    if (l < 2) bias_relu_store(acc, bp + (l + 1) * 256 + et * 128, ab, q, c);
  }

  // layer-3 epilogue: +bias, LDS fp32 transpose (two 64-feature passes), unrolled
  // segmented sum over sorted dst with precomputed masks; plain contiguous 256B
  // store for wave-interior dsts, atomic at wave borders.
  float bias[8];
  #pragma unroll
  for (int j = 0; j < 8; ++j) bias[j] = bp[3 * 256 + et * 128 + c * 8 + j];

  float* fab = (float*)ab;  // 64 rows x 64 feature-slots fp32 (16KB, wave-private)
  #pragma unroll
  for (int half = 0; half < 2; ++half) {
    #pragma unroll
    for (int mt = 0; mt < 4; ++mt) {
      #pragma unroll
      for (int r = 0; r < 4; ++r) {
        const int row = mt * 16 + 4 * q + r;
        f32x4 t;
        #pragma unroll
        for (int nti = 0; nti < 4; ++nti)
          t[nti] = acc[mt][half * 4 + nti][r] + bias[half * 4 + nti];
        *(f32x4*)(fab + row * 64 + c * 4) = t;
      }
    }
    // column `lane` of fab holds pi-slot (lane>>2)*8 + half*4 + (lane&3) == position half*64+lane
    float run = 0.f;
    #pragma unroll
    for (int j = 0; j < 64; ++j) {
      run += fab[j * 64 + lane];
      if ((tails >> j) & 1) {  // wave-uniform flush at run tail
        const int d = __builtin_amdgcn_readlane(dval, j);
        if (d >= 0) {
          float* mp = msgs + (size_t)d * HID + half * 64 + lane;
          if ((intmask >> j) & 1) *mp = run;
          else atomicAdd(mp, run);
        }
        run = 0.f;
      }
    }
  }
}

// ---------------- fused LSTM: gates GEMM (K=512) + activations + score ----------------
// block: 4 waves, 64 cells, full 512 gates (wave w = gate quarter w)
__launch_bounds__(256, 2)
__global__ void lstm_kernel(
    const int step,
    const u16* __restrict__ xb, const float* __restrict__ mm0, const float* __restrict__ mm1,
    u16* __restrict__ h, float* __restrict__ rc,
    const u16* __restrict__ Wcb, const float* __restrict__ swp,
    float* __restrict__ out)
{
  __shared__ u16 at[64 * 512];  // 64KB swizzled: A-tile, then reused for gates exchange
  const int tid = threadIdx.x;
  const int cb = blockIdx.x * 64;

  // stage A = [x | m0 | m1 | rh] as bf16 (rh = 0 at step 0); m is in "epilogue order"
  for (int base = tid * 8; base < 64 * 512; base += 2048) {
    const int cl = base >> 9, s = base & 511;
    const int cell = cb + cl;
    short8 t;
    if (s < 128) {
      t = *(const short8*)(xb + cell * 128 + s);
    } else if (s < 384) {
      const float* mp = (s < 256 ? mm0 : mm1) + cell * 128;
      const int cc = (s & 127) >> 3;
      f32x4 lo = *(const f32x4*)(mp + cc * 4);        // pi-slots 8cc+0..3
      f32x4 hi = *(const f32x4*)(mp + 64 + cc * 4);   // pi-slots 8cc+4..7
      #pragma unroll
      for (int j = 0; j < 4; ++j) { t[j] = (short)f2bf(lo[j]); t[4 + j] = (short)f2bf(hi[j]); }
    } else if (step == 0) {
      #pragma unroll
      for (int j = 0; j < 8; ++j) t[j] = 0;
    } else {
      t = *(const short8*)(h + cell * 128 + (s & 127));
    }
    const int blk = s >> 3;
    const int blks = (blk & 48) | ((blk ^ cl) & 15);
    *(short8*)(at + cl * 512 + blks * 8) = t;
  }
  __syncthreads();

  const int w = tid >> 6, lane = tid & 63, q = lane >> 4, c = lane & 15;
  const f32x4 zf = {0.f, 0.f, 0.f, 0.f};
  f32x4 acc[4][8];
  #pragma unroll
  for (int mt = 0; mt < 4; ++mt)
    #pragma unroll
    for (int nt = 0; nt < 8; ++nt) acc[mt][nt] = zf;

  #pragma unroll
  for (int ks = 0; ks < 16; ++ks) {
    const int kq = ks * 32 + q * 8;
    const int blk = (kq >> 3);  // 0..63
    short8 a[4], b[8];
    #pragma unroll
    for (int mt = 0; mt < 4; ++mt) {
      const int row = mt * 16 + c;
      const int blks = (blk & 48) | ((blk ^ c) & 15);
      a[mt] = *(const short8*)(at + row * 512 + blks * 8);
    }
    #pragma unroll
    for (int nt = 0; nt < 8; ++nt)
      b[nt] = *(const short8*)(Wcb + (w * 128 + nt * 16 + c) * 512 + kq);
    #pragma unroll
    for (int mt = 0; mt < 4; ++mt)
      #pragma unroll
      for (int nt = 0; nt < 8; ++nt)
        acc[mt][nt] = __builtin_amdgcn_mfma_f32_16x16x32_bf16(a[mt], b[nt], acc[mt][nt], 0, 0, 0);
  }
  __syncthreads();

  // exchange gates through LDS (bf16, same swizzle)
  #pragma unroll
  for (int mt = 0; mt < 4; ++mt) {
    #pragma unroll
    for (int r = 0; r < 4; ++r) {
      const int rowl = mt * 16 + 4 * q + r;
      short8 t;
      #pragma unroll
      for (int nt = 0; nt < 8; ++nt) t[nt] = (short)f2bf(acc[mt][nt][r]);
      const int blks = (w << 4) | ((c ^ (rowl & 15)) & 15);
      *(short8*)(at + rowl * 512 + blks * 8) = t;
    }
  }
  __syncthreads();

  // epilogue: lane (w,q,c) -> cell w*16+c, feature chunk q*32..q*32+31 (stored order)
  const int cl = w * 16 + c;
  const int cell = cb + cl;
  float* rcp = rc + cell * 128 + q * 32;
  u16* hp = h + cell * 128 + q * 32;
  const float* swq = swp + q * 32;
  float lsum = 0.f;
  #pragma unroll
  for (int jj = 0; jj < 32; jj += 8) {
    const int bq = q * 4 + (jj >> 3);  // within-quarter block 0..15
    const int bx = (bq ^ cl) & 15;
    short8 iv = *(const short8*)(at + cl * 512 + ((0 << 4) | bx) * 8 + 0);
    short8 fv = *(const short8*)(at + cl * 512 + ((1 << 4) | bx) * 8);
    short8 gv = *(const short8*)(at + cl * 512 + ((2 << 4) | bx) * 8);
    short8 ov = *(const short8*)(at + cl * 512 + ((3 << 4) | bx) * 8);
    short8 nh8;
    #pragma unroll
    for (int j = 0; j < 8; ++j) {
      float ig = sigm(bf2f((u16)iv[j]));
      float fg = sigm(bf2f((u16)fv[j]));
      float gg = tanha(bf2f((u16)gv[j]));
      float og = sigm(bf2f((u16)ov[j]));
      float c0 = rcp[jj + j];
      float nc = fg * c0 + ig * gg;
      float nhv = og * tanha(nc);
      rcp[jj + j] = nc;
      nh8[j] = (short)f2bf(nhv);
      lsum += nhv * swq[jj + j];
    }
    *(short8*)(hp + jj) = nh8;
  }
  lsum += __shfl_xor(lsum, 16);
  lsum += __shfl_xor(lsum, 32);
  if (q == 0) out[step * CELLS + cell] = lsum;
}

extern "C" void kernel_launch(void* const* d_in, const int* in_sizes, int n_in,
                              void* d_out, int out_size, void* d_ws, size_t ws_size,
                              hipStream_t stream)
{
  const int* q      = (const int*)d_in[0];
  const int* esrc   = (const int*)d_in[1];
  const int* edst   = (const int*)d_in[2];
  const float* embed= (const float*)d_in[3];
  const float* W0   = (const float*)d_in[4];
  const float* b0   = (const float*)d_in[5];
  const float* W1   = (const float*)d_in[6];
  const float* b1   = (const float*)d_in[7];
  const float* W2   = (const float*)d_in[8];
  const float* b2   = (const float*)d_in[9];
  const float* W3   = (const float*)d_in[10];
  const float* b3   = (const float*)d_in[11];
  const float* Wih  = (const float*)d_in[12];
  const float* Whh  = (const float*)d_in[13];
  const float* sw   = (const float*)d_in[14];

  char* ws = (char*)d_ws;
  size_t off = 0;
  auto alloc = [&](size_t bytes) {
    void* p = ws + off;
    off += (bytes + 255) & ~(size_t)255;
    return p;
  };
  u16*   h    = (u16*)  alloc((size_t)CELLS * HID * 2);
  u16*   xb   = (u16*)  alloc((size_t)CELLS * HID * 2);
  float* rc   = (float*)alloc((size_t)CELLS * HID * 4);
  float* m0   = (float*)alloc((size_t)CELLS * HID * 4);
  float* m1   = (float*)alloc((size_t)CELLS * HID * 4);
  u16*   W0b  = (u16*)  alloc(2 * 128 * 256 * 2);
  u16*   W1b  = (u16*)  alloc(2 * 128 * 128 * 2);
  u16*   W2b  = (u16*)  alloc(2 * 128 * 128 * 2);
  u16*   W3b  = (u16*)  alloc(2 * 128 * 128 * 2);
  u16*   Wcb  = (u16*)  alloc(512 * 512 * 2);
  float* bp   = (float*)alloc(4 * 256 * 4);
  u16*   embp = (u16*)  alloc(384 * 2);
  float* swp  = (float*)alloc(128 * 4);
  // sort workspace
  int*   counts = (int*)alloc((size_t)2 * CELLS * 4);
  int*   Sarr   = (int*)alloc(((size_t)2 * CELLS + 1) * 4);
  int*   fill   = (int*)alloc((size_t)2 * CELLS * 4);
  int*   btot   = (int*)alloc(192 * 4);
  int*   boffs  = (int*)alloc(192 * 4);
  int*   ssrc   = (int*)alloc((size_t)2 * NE * 4);
  int*   sdst   = (int*)alloc((size_t)2 * NE * 4);

  prep_kernel<<<1670, 256, 0, stream>>>(W0, W1, W2, W3, b0, b1, b2, b3, Wih, Whh, embed, sw,
                                        W0b, W1b, W2b, W3b, Wcb, bp, embp, swp);
  init_kernel<<<(CELLS * HID) / 256, 256, 0, stream>>>(q, embp, xb, h, rc);

  // dst-sort both edge types
  hipMemsetAsync(counts, 0, (size_t)2 * CELLS * 4, stream);
  hipMemsetAsync(fill, 0, (size_t)2 * CELLS * 4, stream);
  hist_kernel<<<(2 * NE + 255) / 256, 256, 0, stream>>>(edst, counts);
  scan1_kernel<<<192, 1024, 0, stream>>>(counts, Sarr, btot);
  scan2_kernel<<<1, 256, 0, stream>>>(btot, boffs, Sarr);
  scan3_kernel<<<192, 1024, 0, stream>>>(Sarr, boffs);
  scatter_kernel<<<(2 * NE + 255) / 256, 256, 0, stream>>>(esrc, edst, Sarr, fill, ssrc, sdst);

  for (int step = 0; step < NSTEPS; ++step) {
    hipMemsetAsync(m0, 0, (size_t)CELLS * HID * 4, stream);
    hipMemsetAsync(m1, 0, (size_t)CELLS * HID * 4, stream);
    msg_kernel<<<dim3((NE + 127) / 128, 2), 128, 0, stream>>>(h, ssrc, sdst, Sarr,
                                                              W0b, W1b, W2b, W3b, bp, m0, m1);
    lstm_kernel<<<CELLS / 64, 256, 0, stream>>>(step, xb, m0, m1, h, rc, Wcb, swp, (float*)d_out);
  }
}